// Round 3
// baseline (1633.900 us; speedup 1.0000x reference)
//
#include <hip/hip_runtime.h>
#include <hip/hip_bf16.h>

typedef __attribute__((ext_vector_type(8))) short bf16x8;
typedef __attribute__((ext_vector_type(8))) unsigned short u16x8;
typedef __attribute__((ext_vector_type(4))) float f32x4;
typedef unsigned short u16;

__device__ __forceinline__ float bf2f(u16 u) {
    union { unsigned int i; float f; } v; v.i = ((unsigned int)u) << 16; return v.f;
}
__device__ __forceinline__ u16 f2bf(float f) {
    union { float f; unsigned int i; } v; v.f = f;
    unsigned int r = v.i + 0x7fffu + ((v.i >> 16) & 1u);
    return (u16)(r >> 16);
}
__device__ __forceinline__ u16x8 pack8(const float4& a, const float4& b) {
    u16x8 r;
    r[0] = f2bf(a.x); r[1] = f2bf(a.y); r[2] = f2bf(a.z); r[3] = f2bf(a.w);
    r[4] = f2bf(b.x); r[5] = f2bf(b.y); r[6] = f2bf(b.z); r[7] = f2bf(b.w);
    return r;
}

// ------- GEMM: C[M,N] = A[M,K] @ B[N,K]^T.  B always fp32 (weights).
// ABF: A is bf16 (internal buffer) else fp32.  OUTF: C fp32 else bf16.
// EPI: 0 none, 1 +ADD[m*N+n] (fp32), 2 relu^2.  TRANS: C[n*ldc+m+m_off].
template <int EPI, bool TRANS, bool ABF, bool OUTF>
__global__ __launch_bounds__(256) void gemm_bt(
    const void* __restrict__ Av, const float* __restrict__ B,
    void* __restrict__ Cv, const float* __restrict__ ADD,
    int M, int N, int K, int ldc, int m_off)
{
    __shared__ alignas(16) u16 As[128 * 32];   // [128 rows][32 k]
    __shared__ alignas(16) u16 Bs[128 * 32];
    const int tid = threadIdx.x;
    const int w = tid >> 6, lane = tid & 63;
    const int col = lane & 15, quad = lane >> 4;
    const long m0 = (long)blockIdx.y * 128, n0 = (long)blockIdx.x * 128;
    const int wr = (w >> 1) * 64, wc = (w & 1) * 64;
    const int srow = tid >> 1;            // 0..127
    const int scol = (tid & 1) * 16;      // 0 or 16

    const f32x4 fzero = {0.f, 0.f, 0.f, 0.f};
    f32x4 acc[4][4];
#pragma unroll
    for (int i = 0; i < 4; ++i)
#pragma unroll
        for (int t = 0; t < 4; ++t) acc[i][t] = fzero;

    const u16*   Ab  = ABF ? (const u16*)Av   + (m0 + srow) * (long)K + scol : nullptr;
    const float* Afp = ABF ? nullptr : (const float*)Av + (m0 + srow) * (long)K + scol;
    const float* Bf  = B + (n0 + srow) * (long)K + scol;
    u16* AsW = &As[srow * 32 + scol];
    u16* BsW = &Bs[srow * 32 + scol];

    for (int k0 = 0; k0 < K; k0 += 32) {
        u16x8 a0, a1, b0, b1;
        if (ABF) {
            a0 = *(const u16x8*)(Ab + k0);
            a1 = *(const u16x8*)(Ab + k0 + 8);
        } else {
            float4 f0 = *(const float4*)(Afp + k0);
            float4 f1 = *(const float4*)(Afp + k0 + 4);
            float4 f2_ = *(const float4*)(Afp + k0 + 8);
            float4 f3 = *(const float4*)(Afp + k0 + 12);
            a0 = pack8(f0, f1); a1 = pack8(f2_, f3);
        }
        {
            float4 g0 = *(const float4*)(Bf + k0);
            float4 g1 = *(const float4*)(Bf + k0 + 4);
            float4 g2 = *(const float4*)(Bf + k0 + 8);
            float4 g3 = *(const float4*)(Bf + k0 + 12);
            b0 = pack8(g0, g1); b1 = pack8(g2, g3);
        }
        __syncthreads();   // prior-iter ds_reads done before overwrite
        *(u16x8*)(AsW)     = a0;
        *(u16x8*)(AsW + 8) = a1;
        *(u16x8*)(BsW)     = b0;
        *(u16x8*)(BsW + 8) = b1;
        __syncthreads();
        bf16x8 af[4], bfr[4];
#pragma unroll
        for (int i = 0; i < 4; ++i)
            af[i] = *(const bf16x8*)&As[(wr + i * 16 + col) * 32 + quad * 8];
#pragma unroll
        for (int t = 0; t < 4; ++t)
            bfr[t] = *(const bf16x8*)&Bs[(wc + t * 16 + col) * 32 + quad * 8];
#pragma unroll
        for (int i = 0; i < 4; ++i)
#pragma unroll
            for (int t = 0; t < 4; ++t)
                acc[i][t] = __builtin_amdgcn_mfma_f32_16x16x32_bf16(af[i], bfr[t], acc[i][t], 0, 0, 0);
    }

#pragma unroll
    for (int i = 0; i < 4; ++i)
#pragma unroll
        for (int t = 0; t < 4; ++t)
#pragma unroll
            for (int r = 0; r < 4; ++r) {
                const long m = m0 + wr + i * 16 + quad * 4 + r;  // C/D: row = quad*4+reg
                const long n = n0 + wc + t * 16 + col;           // C/D: col = lane&15
                float v = acc[i][t][r];
                if (EPI == 1) v += ADD[m * N + n];
                if (EPI == 2) { float rv = v > 0.f ? v : 0.f; v = rv * rv; }
                const long idx = TRANS ? (n * (long)ldc + m + m_off)
                                       : ((m + m_off) * (long)ldc + n);
                if (OUTF) ((float*)Cv)[idx] = v;
                else      ((u16*)Cv)[idx]   = f2bf(v);
            }
}

// ------- RMSNorm: fp32 in (X, W), bf16 out.  One block per row of 2048. -------
__global__ __launch_bounds__(256) void rmsnorm_k(
    const float* __restrict__ X, const float* __restrict__ W, u16* __restrict__ out)
{
    const int row = blockIdx.x, tid = threadIdx.x;
    const float* xr = X + (long)row * 2048 + tid * 8;
    float4 x0 = *(const float4*)xr;
    float4 x1 = *(const float4*)(xr + 4);
    float xs[8] = {x0.x, x0.y, x0.z, x0.w, x1.x, x1.y, x1.z, x1.w};
    float local = 0.f;
#pragma unroll
    for (int j = 0; j < 8; ++j) local += xs[j] * xs[j];
#pragma unroll
    for (int off = 32; off >= 1; off >>= 1) local += __shfl_xor(local, off, 64);
    __shared__ float ssum[4];
    if ((tid & 63) == 0) ssum[tid >> 6] = local;
    __syncthreads();
    const float tot = ssum[0] + ssum[1] + ssum[2] + ssum[3];
    const float rs = rsqrtf(tot * (1.f / 2048.f) + 1e-5f);
    float4 w0 = *(const float4*)(W + tid * 8);
    float4 w1 = *(const float4*)(W + tid * 8 + 4);
    float ws[8] = {w0.x, w0.y, w0.z, w0.w, w1.x, w1.y, w1.z, w1.w};
    u16x8 ov;
#pragma unroll
    for (int j = 0; j < 8; ++j) ov[j] = f2bf(xs[j] * rs * ws[j]);
    *(u16x8*)(out + (long)row * 2048 + tid * 8) = ov;
}

// ------- RoPE in-place on bf16 [2048][ncols], 64-wide head chunks -------------
__global__ __launch_bounds__(256) void rope_k(
    u16* __restrict__ T, int ncols, const int* __restrict__ pos)
{
    const int s = blockIdx.x;
    const float p = (float)pos[s];
    u16* row = T + (long)s * ncols;
    for (int idx = threadIdx.x; idx < (ncols >> 1); idx += 256) {
        const int chunk = idx >> 5, d = idx & 31;
        const float inv = expf(-0.28782313662425572f * (float)d); // 10000^(-d/32)
        const float ang = p * inv;
        const float c = cosf(ang), sn = sinf(ang);
        const int i0 = chunk * 64 + d;
        const float x0 = bf2f(row[i0]), x1 = bf2f(row[i0 + 32]);
        row[i0]      = f2bf(x0 * c - x1 * sn);
        row[i0 + 32] = f2bf(x1 * c + x0 * sn);
    }
}

// ------- sink token (fp32 in) into kb_k row 0 / kb_vT col 0; zero kbk tail ----
__global__ void sink_copy(const float* __restrict__ sk, const float* __restrict__ sv,
                          u16* __restrict__ kbk, u16* __restrict__ kbvT)
{
    const int i = blockIdx.x * 256 + threadIdx.x;
    if (i < 512) { kbk[i] = f2bf(sk[i]); kbvT[(long)i * 320] = f2bf(sv[i]); }
}
__global__ void kbk_clear(u16* __restrict__ kbk)
{
    const int i = blockIdx.x * 256 + threadIdx.x;     // 63*512 = 32256 elems
    if (i < 63 * 512) kbk[257 * 512 + i] = 0;
}

// ------- Rectangular attention (KB || causal self, joint softmax), bf16 -------
// grid (qt=32, h=32), 256 thr. Wave w owns q rows [s0+16w, s0+16w+16).
__global__ __launch_bounds__(256) void attn_kernel(
    const u16* __restrict__ Q,    // [2048][2048] rope'd
    const u16* __restrict__ QN,   // [2048][2048] (no rope)
    const u16* __restrict__ Ks,   // [2048][512]  rope'd
    const u16* __restrict__ VT,   // [512][2048]  V^T
    const u16* __restrict__ KBK,  // [320][512]   row0 sink, 257.. zeroed
    const u16* __restrict__ KBVT, // [512][320]   col0 sink
    u16* __restrict__ O)          // [2048][2048]
{
    const int qt = blockIdx.x, h = blockIdx.y;
    const int s0 = qt * 64, kv = h >> 2;
    const int tid = threadIdx.x, w = tid >> 6, lane = tid & 63;
    const int col = lane & 15, quad = lane >> 4;
    const int rowbase = s0 + w * 16;
    __shared__ alignas(16) u16 Plds[4][16][64];
    const f32x4 fzero = {0.f, 0.f, 0.f, 0.f};

    bf16x8 af[2][2];  // [phase][k-chunk]; A-layout: m=lane&15, k=quad*8+j
    {
        const u16* qp = QN + (long)(rowbase + col) * 2048 + h * 64 + quad * 8;
        af[0][0] = *(const bf16x8*)qp;
        af[0][1] = *(const bf16x8*)(qp + 32);
        const u16* qp2 = Q + (long)(rowbase + col) * 2048 + h * 64 + quad * 8;
        af[1][0] = *(const bf16x8*)qp2;
        af[1][1] = *(const bf16x8*)(qp2 + 32);
    }
    float m_run[4], l_run[4];
    f32x4 o_acc[4];
#pragma unroll
    for (int r = 0; r < 4; ++r) { m_run[r] = -1e30f; l_run[r] = 0.f; }
#pragma unroll
    for (int t = 0; t < 4; ++t) o_acc[t] = fzero;

    for (int phase = 0; phase < 2; ++phase) {
        const u16* Kp = phase ? Ks : KBK;
        const u16* Vp = phase ? VT : KBVT;
        const long ldv = phase ? 2048 : 320;
        const int iters = phase ? (qt + 1) : 5;      // uniform per block
        const bf16x8 a0 = af[phase][0], a1 = af[phase][1];
        for (int it = 0; it < iters; ++it) {
            const int key0 = it * 64;
            f32x4 sv[4];
#pragma unroll
            for (int t = 0; t < 4; ++t) {
                const u16* kp = Kp + (long)(key0 + t * 16 + col) * 512 + kv * 64 + quad * 8;
                bf16x8 k0v = *(const bf16x8*)kp;
                bf16x8 k1v = *(const bf16x8*)(kp + 32);
                f32x4 z = fzero;
                z = __builtin_amdgcn_mfma_f32_16x16x32_bf16(a0, k0v, z, 0, 0, 0);
                sv[t] = __builtin_amdgcn_mfma_f32_16x16x32_bf16(a1, k1v, z, 0, 0, 0);
            }
            float rmax[4] = {-3e38f, -3e38f, -3e38f, -3e38f};
#pragma unroll
            for (int t = 0; t < 4; ++t)
#pragma unroll
                for (int r = 0; r < 4; ++r) {
                    float s_ = sv[t][r] * 0.125f;
                    const int key = key0 + t * 16 + col;
                    const bool msk = phase ? (key > rowbase + quad * 4 + r) : (key >= 257);
                    s_ = msk ? -1e9f : s_;
                    sv[t][r] = s_;
                    rmax[r] = fmaxf(rmax[r], s_);
                }
#pragma unroll
            for (int off = 1; off < 16; off <<= 1)
#pragma unroll
                for (int r = 0; r < 4; ++r)
                    rmax[r] = fmaxf(rmax[r], __shfl_xor(rmax[r], off, 64));
            float alpha[4], psum[4];
#pragma unroll
            for (int r = 0; r < 4; ++r) {
                const float mn = fmaxf(m_run[r], rmax[r]);
                alpha[r] = __expf(m_run[r] - mn);
                m_run[r] = mn;
                psum[r] = 0.f;
            }
#pragma unroll
            for (int t = 0; t < 4; ++t)
#pragma unroll
                for (int r = 0; r < 4; ++r) {
                    const float p = __expf(sv[t][r] - m_run[r]);
                    psum[r] += p;
                    Plds[w][quad * 4 + r][t * 16 + col] = f2bf(p);  // C-layout dump
                }
#pragma unroll
            for (int off = 1; off < 16; off <<= 1)
#pragma unroll
                for (int r = 0; r < 4; ++r)
                    psum[r] += __shfl_xor(psum[r], off, 64);
#pragma unroll
            for (int r = 0; r < 4; ++r) l_run[r] = l_run[r] * alpha[r] + psum[r];
#pragma unroll
            for (int t = 0; t < 4; ++t)
#pragma unroll
                for (int r = 0; r < 4; ++r) o_acc[t][r] *= alpha[r];
            __syncthreads();  // P visible before A-layout re-read
            const bf16x8 p0 = *(const bf16x8*)&Plds[w][col][quad * 8];       // A-layout read
            const bf16x8 p1 = *(const bf16x8*)&Plds[w][col][32 + quad * 8];
#pragma unroll
            for (int t = 0; t < 4; ++t) {
                const u16* vp = Vp + (long)(kv * 64 + t * 16 + col) * ldv + key0 + quad * 8;
                bf16x8 v0 = *(const bf16x8*)vp;
                bf16x8 v1 = *(const bf16x8*)(vp + 32);
                o_acc[t] = __builtin_amdgcn_mfma_f32_16x16x32_bf16(p0, v0, o_acc[t], 0, 0, 0);
                o_acc[t] = __builtin_amdgcn_mfma_f32_16x16x32_bf16(p1, v1, o_acc[t], 0, 0, 0);
            }
            __syncthreads();  // reads done before next-iter P writes
        }
    }
#pragma unroll
    for (int t = 0; t < 4; ++t)
#pragma unroll
        for (int r = 0; r < 4; ++r) {
            const long m = rowbase + quad * 4 + r;
            const long n = h * 64 + t * 16 + col;
            O[m * 2048 + n] = f2bf(o_acc[t][r] / l_run[r]);
        }
}

// ---------------- launcher ----------------------------------------------------
extern "C" void kernel_launch(void* const* d_in, const int* in_sizes, int n_in,
                              void* d_out, int out_size, void* d_ws, size_t ws_size,
                              hipStream_t stream)
{
    // All external tensors are FP32 (per reference dtypes); pos_ids int32.
    const float* hidden  = (const float*)d_in[0];
    const float* kb_keys = (const float*)d_in[1];
    const float* kb_vals = (const float*)d_in[2];
    const float* q_w     = (const float*)d_in[3];
    const float* k_w     = (const float*)d_in[4];
    const float* v_w     = (const float*)d_in[5];
    const float* o_w     = (const float*)d_in[6];
    const float* qnew_w  = (const float*)d_in[7];
    const float* kbk_w   = (const float*)d_in[8];
    const float* kbv_w   = (const float*)d_in[9];
    const float* sink_k  = (const float*)d_in[10];
    const float* sink_v  = (const float*)d_in[11];
    const float* ln1_w   = (const float*)d_in[12];
    const float* ln2_w   = (const float*)d_in[13];
    const float* up_w    = (const float*)d_in[14];
    const float* down_w  = (const float*)d_in[15];
    const int*   pos_ids = (const int*)d_in[16];
    float* out = (float*)d_out;

    // Workspace: 56 MB.  act (bf16, 32MB) overlaps dead q/qn/k/vT/kb/attn.
    char* ws = (char*)d_ws;
    u16*   xn   = (u16*)(ws);                                // bf16 [2048][2048]  0..8MB
    float* hbuf = (float*)(ws + (8L  << 20));                // fp32 [2048][2048]  8..24MB
    u16*   q    = (u16*)(ws + (24L << 20));                  // bf16 [2048][2048] 24..32MB
    u16*   qn   = (u16*)(ws + (32L << 20));                  // bf16 [2048][2048] 32..40MB
    u16*   k    = (u16*)(ws + (40L << 20));                  // bf16 [2048][512]  40..42MB
    u16*   vT   = (u16*)(ws + (42L << 20));                  // bf16 [512][2048]  42..44MB
    u16*   kbk  = (u16*)(ws + (44L << 20));                  // bf16 [320][512]
    u16*   kbvT = (u16*)(ws + (44L << 20) + 320 * 512 * 2);  // bf16 [512][320]
    u16*   attn = (u16*)(ws + (45L << 20));                  // bf16 [2048][2048] 45..53MB
    u16*   act  = (u16*)(ws + (24L << 20));                  // bf16 [2048][8192] 24..56MB (later)

    const dim3 blk(256);
    rmsnorm_k<<<2048, blk, 0, stream>>>(hidden, ln1_w, xn);

    gemm_bt<0, false, true,  false><<<dim3(16, 16), blk, 0, stream>>>(xn, q_w,    q,    nullptr, 2048, 2048, 2048, 2048, 0);
    gemm_bt<0, false, true,  false><<<dim3(4, 16),  blk, 0, stream>>>(xn, k_w,    k,    nullptr, 2048, 512,  2048, 512,  0);
    gemm_bt<0, true,  true,  false><<<dim3(4, 16),  blk, 0, stream>>>(xn, v_w,    vT,   nullptr, 2048, 512,  2048, 2048, 0);
    gemm_bt<0, false, true,  false><<<dim3(16, 16), blk, 0, stream>>>(xn, qnew_w, qn,   nullptr, 2048, 2048, 2048, 2048, 0);
    gemm_bt<0, false, false, false><<<dim3(4, 2),   blk, 0, stream>>>(kb_keys, kbk_w, kbk,  nullptr, 256, 512, 2048, 512, 1);
    gemm_bt<0, true,  false, false><<<dim3(4, 2),   blk, 0, stream>>>(kb_vals, kbv_w, kbvT, nullptr, 256, 512, 2048, 320, 1);
    sink_copy<<<2, blk, 0, stream>>>(sink_k, sink_v, kbk, kbvT);
    kbk_clear<<<126, blk, 0, stream>>>(kbk);

    rope_k<<<2048, blk, 0, stream>>>(q, 2048, pos_ids);
    rope_k<<<2048, blk, 0, stream>>>(k, 512, pos_ids);

    attn_kernel<<<dim3(32, 32), blk, 0, stream>>>(q, qn, k, vT, kbk, kbvT, attn);

    // o-proj + residual (fp32 hidden) -> fp32 hbuf
    gemm_bt<1, false, true, true ><<<dim3(16, 16), blk, 0, stream>>>(attn, o_w, hbuf, hidden, 2048, 2048, 2048, 2048, 0);
    rmsnorm_k<<<2048, blk, 0, stream>>>(hbuf, ln2_w, xn);
    // up-proj + relu^2 -> bf16 act
    gemm_bt<2, false, true, false><<<dim3(64, 16), blk, 0, stream>>>(xn, up_w, act, nullptr, 2048, 8192, 2048, 8192, 0);
    // down-proj + residual (fp32 hbuf) -> fp32 out
    gemm_bt<1, false, true, true ><<<dim3(16, 16), blk, 0, stream>>>(act, down_w, out, hbuf, 2048, 2048, 8192, 2048, 0);
}

// Round 4
// 1205.611 us; speedup vs baseline: 1.3552x; 1.3552x over previous
//
#include <hip/hip_runtime.h>
#include <hip/hip_bf16.h>

typedef __attribute__((ext_vector_type(8))) short bf16x8;
typedef __attribute__((ext_vector_type(8))) unsigned short u16x8;
typedef __attribute__((ext_vector_type(4))) float f32x4;
typedef unsigned short u16;

__device__ __forceinline__ float bf2f(u16 u) {
    union { unsigned int i; float f; } v; v.i = ((unsigned int)u) << 16; return v.f;
}
__device__ __forceinline__ u16 f2bf(float f) {
    union { float f; unsigned int i; } v; v.f = f;
    unsigned int r = v.i + 0x7fffu + ((v.i >> 16) & 1u);
    return (u16)(r >> 16);
}
__device__ __forceinline__ u16x8 pack8(const float4& a, const float4& b) {
    u16x8 r;
    r[0] = f2bf(a.x); r[1] = f2bf(a.y); r[2] = f2bf(a.z); r[3] = f2bf(a.w);
    r[4] = f2bf(b.x); r[5] = f2bf(b.y); r[6] = f2bf(b.z); r[7] = f2bf(b.w);
    return r;
}

#define GLD16(gp, lp) __builtin_amdgcn_global_load_lds( \
    (const __attribute__((address_space(1))) void*)(gp), \
    (__attribute__((address_space(3))) void*)(lp), 16, 0, 0)

// ======== FAST GEMM (all-bf16, global_load_lds 16B staging, m97 structure) ====
// C[M,N] = A[M,K] @ B[N,K]^T.  EPI: 0 none, 1 +ADD[m*N+n] (fp32), 2 relu^2.
// TRANS: store C[n*ldc + m + m_off].  OUTF: C fp32 else bf16.
template <int EPI, bool TRANS, bool OUTF>
__global__ __launch_bounds__(256) void gemm_fast(
    const u16* __restrict__ A, const u16* __restrict__ B,
    void* __restrict__ Cv, const float* __restrict__ ADD,
    int M, int N, int K, int ldc, int m_off)
{
    __shared__ u16 As[128 * 32];   // [128 rows][32 k] unpadded (GLD contract)
    __shared__ u16 Bs[128 * 32];
    const int tid = threadIdx.x;
    const int w = tid >> 6, lane = tid & 63;
    const int col = lane & 15, quad = lane >> 4;
    const long m0 = (long)blockIdx.y * 128, n0 = (long)blockIdx.x * 128;
    const int wr = (w >> 1) * 64, wc = (w & 1) * 64;
    const int srow = lane >> 2;          // 0..15
    const int scol = (lane & 3) * 8;     // element col within 32-wide k-tile

    const f32x4 fzero = {0.f, 0.f, 0.f, 0.f};
    f32x4 acc[4][4];
#pragma unroll
    for (int i = 0; i < 4; ++i)
#pragma unroll
        for (int t = 0; t < 4; ++t) acc[i][t] = fzero;

    const u16* Ab = A + m0 * (long)K + scol;
    const u16* Bb = B + n0 * (long)K + scol;
    for (int k0 = 0; k0 < K; k0 += 32) {
        __syncthreads();   // prior-iter ds_reads done before overwrite
#pragma unroll
        for (int c = 0; c < 2; ++c) {
            const int rr = w * 32 + c * 16;   // wave-uniform LDS base
            GLD16(Ab + (long)(rr + srow) * K + k0, &As[rr * 32]);
            GLD16(Bb + (long)(rr + srow) * K + k0, &Bs[rr * 32]);
        }
        __syncthreads();   // compiler drains vmcnt before barrier
        bf16x8 af[4], bfr[4];
#pragma unroll
        for (int i = 0; i < 4; ++i)
            af[i] = *(const bf16x8*)&As[(wr + i * 16 + col) * 32 + quad * 8];
#pragma unroll
        for (int t = 0; t < 4; ++t)
            bfr[t] = *(const bf16x8*)&Bs[(wc + t * 16 + col) * 32 + quad * 8];
#pragma unroll
        for (int i = 0; i < 4; ++i)
#pragma unroll
            for (int t = 0; t < 4; ++t)
                acc[i][t] = __builtin_amdgcn_mfma_f32_16x16x32_bf16(af[i], bfr[t], acc[i][t], 0, 0, 0);
    }

#pragma unroll
    for (int i = 0; i < 4; ++i)
#pragma unroll
        for (int t = 0; t < 4; ++t)
#pragma unroll
            for (int r = 0; r < 4; ++r) {
                const long m = m0 + wr + i * 16 + quad * 4 + r;  // C/D: row = quad*4+reg
                const long n = n0 + wc + t * 16 + col;           // C/D: col = lane&15
                float v = acc[i][t][r];
                if (EPI == 1) v += ADD[m * N + n];
                if (EPI == 2) { float rv = v > 0.f ? v : 0.f; v = rv * rv; }
                const long idx = TRANS ? (n * (long)ldc + m + m_off)
                                       : ((m + m_off) * (long)ldc + n);
                if (OUTF) ((float*)Cv)[idx] = v;
                else      ((u16*)Cv)[idx]   = f2bf(v);
            }
}

// ======== FALLBACK GEMM (round-3, fp32 B) =====================================
template <int EPI, bool TRANS, bool ABF, bool OUTF>
__global__ __launch_bounds__(256) void gemm_bt(
    const void* __restrict__ Av, const float* __restrict__ B,
    void* __restrict__ Cv, const float* __restrict__ ADD,
    int M, int N, int K, int ldc, int m_off)
{
    __shared__ alignas(16) u16 As[128 * 32];
    __shared__ alignas(16) u16 Bs[128 * 32];
    const int tid = threadIdx.x;
    const int w = tid >> 6, lane = tid & 63;
    const int col = lane & 15, quad = lane >> 4;
    const long m0 = (long)blockIdx.y * 128, n0 = (long)blockIdx.x * 128;
    const int wr = (w >> 1) * 64, wc = (w & 1) * 64;
    const int srow = tid >> 1;
    const int scol = (tid & 1) * 16;

    const f32x4 fzero = {0.f, 0.f, 0.f, 0.f};
    f32x4 acc[4][4];
#pragma unroll
    for (int i = 0; i < 4; ++i)
#pragma unroll
        for (int t = 0; t < 4; ++t) acc[i][t] = fzero;

    const u16*   Ab  = ABF ? (const u16*)Av   + (m0 + srow) * (long)K + scol : nullptr;
    const float* Afp = ABF ? nullptr : (const float*)Av + (m0 + srow) * (long)K + scol;
    const float* Bf  = B + (n0 + srow) * (long)K + scol;
    u16* AsW = &As[srow * 32 + scol];
    u16* BsW = &Bs[srow * 32 + scol];

    for (int k0 = 0; k0 < K; k0 += 32) {
        u16x8 a0, a1, b0, b1;
        if (ABF) {
            a0 = *(const u16x8*)(Ab + k0);
            a1 = *(const u16x8*)(Ab + k0 + 8);
        } else {
            float4 f0 = *(const float4*)(Afp + k0);
            float4 f1 = *(const float4*)(Afp + k0 + 4);
            float4 f2_ = *(const float4*)(Afp + k0 + 8);
            float4 f3 = *(const float4*)(Afp + k0 + 12);
            a0 = pack8(f0, f1); a1 = pack8(f2_, f3);
        }
        {
            float4 g0 = *(const float4*)(Bf + k0);
            float4 g1 = *(const float4*)(Bf + k0 + 4);
            float4 g2 = *(const float4*)(Bf + k0 + 8);
            float4 g3 = *(const float4*)(Bf + k0 + 12);
            b0 = pack8(g0, g1); b1 = pack8(g2, g3);
        }
        __syncthreads();
        *(u16x8*)(AsW)     = a0;
        *(u16x8*)(AsW + 8) = a1;
        *(u16x8*)(BsW)     = b0;
        *(u16x8*)(BsW + 8) = b1;
        __syncthreads();
        bf16x8 af[4], bfr[4];
#pragma unroll
        for (int i = 0; i < 4; ++i)
            af[i] = *(const bf16x8*)&As[(wr + i * 16 + col) * 32 + quad * 8];
#pragma unroll
        for (int t = 0; t < 4; ++t)
            bfr[t] = *(const bf16x8*)&Bs[(wc + t * 16 + col) * 32 + quad * 8];
#pragma unroll
        for (int i = 0; i < 4; ++i)
#pragma unroll
            for (int t = 0; t < 4; ++t)
                acc[i][t] = __builtin_amdgcn_mfma_f32_16x16x32_bf16(af[i], bfr[t], acc[i][t], 0, 0, 0);
    }

#pragma unroll
    for (int i = 0; i < 4; ++i)
#pragma unroll
        for (int t = 0; t < 4; ++t)
#pragma unroll
            for (int r = 0; r < 4; ++r) {
                const long m = m0 + wr + i * 16 + quad * 4 + r;
                const long n = n0 + wc + t * 16 + col;
                float v = acc[i][t][r];
                if (EPI == 1) v += ADD[m * N + n];
                if (EPI == 2) { float rv = v > 0.f ? v : 0.f; v = rv * rv; }
                const long idx = TRANS ? (n * (long)ldc + m + m_off)
                                       : ((m + m_off) * (long)ldc + n);
                if (OUTF) ((float*)Cv)[idx] = v;
                else      ((u16*)Cv)[idx]   = f2bf(v);
            }
}

// ======== fp32 -> bf16 bulk convert (memory-bound) ============================
__global__ __launch_bounds__(256) void cvt_bf16(
    const float* __restrict__ in, u16* __restrict__ out, int n)
{
    const long i = ((long)blockIdx.x * 256 + threadIdx.x) * 8;
    if (i + 8 <= n) {
        float4 f0 = *(const float4*)(in + i);
        float4 f1 = *(const float4*)(in + i + 4);
        *(u16x8*)(out + i) = pack8(f0, f1);
    }
}

// ======== RMSNorm: fp32 in (X, W), bf16 out ===================================
__global__ __launch_bounds__(256) void rmsnorm_k(
    const float* __restrict__ X, const float* __restrict__ W, u16* __restrict__ out)
{
    const int row = blockIdx.x, tid = threadIdx.x;
    const float* xr = X + (long)row * 2048 + tid * 8;
    float4 x0 = *(const float4*)xr;
    float4 x1 = *(const float4*)(xr + 4);
    float xs[8] = {x0.x, x0.y, x0.z, x0.w, x1.x, x1.y, x1.z, x1.w};
    float local = 0.f;
#pragma unroll
    for (int j = 0; j < 8; ++j) local += xs[j] * xs[j];
#pragma unroll
    for (int off = 32; off >= 1; off >>= 1) local += __shfl_xor(local, off, 64);
    __shared__ float ssum[4];
    if ((tid & 63) == 0) ssum[tid >> 6] = local;
    __syncthreads();
    const float tot = ssum[0] + ssum[1] + ssum[2] + ssum[3];
    const float rs = rsqrtf(tot * (1.f / 2048.f) + 1e-5f);
    float4 w0 = *(const float4*)(W + tid * 8);
    float4 w1 = *(const float4*)(W + tid * 8 + 4);
    float wsv[8] = {w0.x, w0.y, w0.z, w0.w, w1.x, w1.y, w1.z, w1.w};
    u16x8 ov;
#pragma unroll
    for (int j = 0; j < 8; ++j) ov[j] = f2bf(xs[j] * rs * wsv[j]);
    *(u16x8*)(out + (long)row * 2048 + tid * 8) = ov;
}

// ======== RoPE in-place on bf16 [2048][ncols] =================================
__global__ __launch_bounds__(256) void rope_k(
    u16* __restrict__ T, int ncols, const int* __restrict__ pos)
{
    const int s = blockIdx.x;
    const float p = (float)pos[s];
    u16* row = T + (long)s * ncols;
    for (int idx = threadIdx.x; idx < (ncols >> 1); idx += 256) {
        const int chunk = idx >> 5, d = idx & 31;
        const float inv = expf(-0.28782313662425572f * (float)d); // 10000^(-d/32)
        const float ang = p * inv;
        const float c = cosf(ang), sn = sinf(ang);
        const int i0 = chunk * 64 + d;
        const float x0 = bf2f(row[i0]), x1 = bf2f(row[i0 + 32]);
        row[i0]      = f2bf(x0 * c - x1 * sn);
        row[i0 + 32] = f2bf(x1 * c + x0 * sn);
    }
}

// ======== sink token + kbk tail clear =========================================
__global__ void sink_copy(const float* __restrict__ sk, const float* __restrict__ sv,
                          u16* __restrict__ kbk, u16* __restrict__ kbvT)
{
    const int i = blockIdx.x * 256 + threadIdx.x;
    if (i < 512) { kbk[i] = f2bf(sk[i]); kbvT[(long)i * 320] = f2bf(sv[i]); }
}
__global__ void kbk_clear(u16* __restrict__ kbk)
{
    const int i = blockIdx.x * 256 + threadIdx.x;
    if (i < 63 * 512) kbk[257 * 512 + i] = 0;
}

// ======== Rectangular attention (KB || causal self, joint softmax) ============
__global__ __launch_bounds__(256) void attn_kernel(
    const u16* __restrict__ Q, const u16* __restrict__ QN,
    const u16* __restrict__ Ks, const u16* __restrict__ VT,
    const u16* __restrict__ KBK, const u16* __restrict__ KBVT,
    u16* __restrict__ O)
{
    const int qt = blockIdx.x, h = blockIdx.y;
    const int s0 = qt * 64, kv = h >> 2;
    const int tid = threadIdx.x, w = tid >> 6, lane = tid & 63;
    const int col = lane & 15, quad = lane >> 4;
    const int rowbase = s0 + w * 16;
    __shared__ alignas(16) u16 Plds[4][16][64];
    const f32x4 fzero = {0.f, 0.f, 0.f, 0.f};

    bf16x8 af[2][2];
    {
        const u16* qp = QN + (long)(rowbase + col) * 2048 + h * 64 + quad * 8;
        af[0][0] = *(const bf16x8*)qp;
        af[0][1] = *(const bf16x8*)(qp + 32);
        const u16* qp2 = Q + (long)(rowbase + col) * 2048 + h * 64 + quad * 8;
        af[1][0] = *(const bf16x8*)qp2;
        af[1][1] = *(const bf16x8*)(qp2 + 32);
    }
    float m_run[4], l_run[4];
    f32x4 o_acc[4];
#pragma unroll
    for (int r = 0; r < 4; ++r) { m_run[r] = -1e30f; l_run[r] = 0.f; }
#pragma unroll
    for (int t = 0; t < 4; ++t) o_acc[t] = fzero;

    for (int phase = 0; phase < 2; ++phase) {
        const u16* Kp = phase ? Ks : KBK;
        const u16* Vp = phase ? VT : KBVT;
        const long ldv = phase ? 2048 : 320;
        const int iters = phase ? (qt + 1) : 5;
        const bf16x8 a0 = af[phase][0], a1 = af[phase][1];
        for (int it = 0; it < iters; ++it) {
            const int key0 = it * 64;
            f32x4 sv[4];
#pragma unroll
            for (int t = 0; t < 4; ++t) {
                const u16* kp = Kp + (long)(key0 + t * 16 + col) * 512 + kv * 64 + quad * 8;
                bf16x8 k0v = *(const bf16x8*)kp;
                bf16x8 k1v = *(const bf16x8*)(kp + 32);
                f32x4 z = fzero;
                z = __builtin_amdgcn_mfma_f32_16x16x32_bf16(a0, k0v, z, 0, 0, 0);
                sv[t] = __builtin_amdgcn_mfma_f32_16x16x32_bf16(a1, k1v, z, 0, 0, 0);
            }
            float rmax[4] = {-3e38f, -3e38f, -3e38f, -3e38f};
#pragma unroll
            for (int t = 0; t < 4; ++t)
#pragma unroll
                for (int r = 0; r < 4; ++r) {
                    float s_ = sv[t][r] * 0.125f;
                    const int key = key0 + t * 16 + col;
                    const bool msk = phase ? (key > rowbase + quad * 4 + r) : (key >= 257);
                    s_ = msk ? -1e9f : s_;
                    sv[t][r] = s_;
                    rmax[r] = fmaxf(rmax[r], s_);
                }
#pragma unroll
            for (int off = 1; off < 16; off <<= 1)
#pragma unroll
                for (int r = 0; r < 4; ++r)
                    rmax[r] = fmaxf(rmax[r], __shfl_xor(rmax[r], off, 64));
            float alpha[4], psum[4];
#pragma unroll
            for (int r = 0; r < 4; ++r) {
                const float mn = fmaxf(m_run[r], rmax[r]);
                alpha[r] = __expf(m_run[r] - mn);
                m_run[r] = mn;
                psum[r] = 0.f;
            }
#pragma unroll
            for (int t = 0; t < 4; ++t)
#pragma unroll
                for (int r = 0; r < 4; ++r) {
                    const float p = __expf(sv[t][r] - m_run[r]);
                    psum[r] += p;
                    Plds[w][quad * 4 + r][t * 16 + col] = f2bf(p);
                }
#pragma unroll
            for (int off = 1; off < 16; off <<= 1)
#pragma unroll
                for (int r = 0; r < 4; ++r)
                    psum[r] += __shfl_xor(psum[r], off, 64);
#pragma unroll
            for (int r = 0; r < 4; ++r) l_run[r] = l_run[r] * alpha[r] + psum[r];
#pragma unroll
            for (int t = 0; t < 4; ++t)
#pragma unroll
                for (int r = 0; r < 4; ++r) o_acc[t][r] *= alpha[r];
            __syncthreads();
            const bf16x8 p0 = *(const bf16x8*)&Plds[w][col][quad * 8];
            const bf16x8 p1 = *(const bf16x8*)&Plds[w][col][32 + quad * 8];
#pragma unroll
            for (int t = 0; t < 4; ++t) {
                const u16* vp = Vp + (long)(kv * 64 + t * 16 + col) * ldv + key0 + quad * 8;
                bf16x8 v0 = *(const bf16x8*)vp;
                bf16x8 v1 = *(const bf16x8*)(vp + 32);
                o_acc[t] = __builtin_amdgcn_mfma_f32_16x16x32_bf16(p0, v0, o_acc[t], 0, 0, 0);
                o_acc[t] = __builtin_amdgcn_mfma_f32_16x16x32_bf16(p1, v1, o_acc[t], 0, 0, 0);
            }
            __syncthreads();
        }
    }
#pragma unroll
    for (int t = 0; t < 4; ++t)
#pragma unroll
        for (int r = 0; r < 4; ++r) {
            const long m = rowbase + quad * 4 + r;
            const long n = h * 64 + t * 16 + col;
            O[m * 2048 + n] = f2bf(o_acc[t][r] / l_run[r]);
        }
}

// ======== launcher ============================================================
extern "C" void kernel_launch(void* const* d_in, const int* in_sizes, int n_in,
                              void* d_out, int out_size, void* d_ws, size_t ws_size,
                              hipStream_t stream)
{
    const float* hidden  = (const float*)d_in[0];
    const float* kb_keys = (const float*)d_in[1];
    const float* kb_vals = (const float*)d_in[2];
    const float* q_w     = (const float*)d_in[3];
    const float* k_w     = (const float*)d_in[4];
    const float* v_w     = (const float*)d_in[5];
    const float* o_w     = (const float*)d_in[6];
    const float* qnew_w  = (const float*)d_in[7];
    const float* kbk_w   = (const float*)d_in[8];
    const float* kbv_w   = (const float*)d_in[9];
    const float* sink_k  = (const float*)d_in[10];
    const float* sink_v  = (const float*)d_in[11];
    const float* ln1_w   = (const float*)d_in[12];
    const float* ln2_w   = (const float*)d_in[13];
    const float* up_w    = (const float*)d_in[14];
    const float* down_w  = (const float*)d_in[15];
    const int*   pos_ids = (const int*)d_in[16];
    float* out = (float*)d_out;

    // Activations: 56 MB (act overlaps dead q/qn/k/vT/kb/attn).
    char* ws = (char*)d_ws;
    u16*   xn   = (u16*)(ws);                                // bf16 [2048][2048]  0..8MB
    float* hbuf = (float*)(ws + (8L  << 20));                // fp32 [2048][2048]  8..24MB
    u16*   q    = (u16*)(ws + (24L << 20));                  // bf16 24..32MB
    u16*   qn   = (u16*)(ws + (32L << 20));                  // bf16 32..40MB
    u16*   k    = (u16*)(ws + (40L << 20));                  // bf16 40..42MB
    u16*   vT   = (u16*)(ws + (42L << 20));                  // bf16 42..44MB
    u16*   kbk  = (u16*)(ws + (44L << 20));                  // bf16 [320][512]
    u16*   kbvT = (u16*)(ws + (44L << 20) + 320 * 512 * 2);  // bf16 [512][320]
    u16*   attn = (u16*)(ws + (45L << 20));                  // bf16 45..53MB
    u16*   act  = (u16*)(ws + (24L << 20));                  // bf16 24..56MB (after attn)

    // bf16 weight cache: 56..154 MB
    u16* wq   = (u16*)(ws + (56L  << 20));   // 4M elem
    u16* wk   = (u16*)(ws + (64L  << 20));   // 1M
    u16* wv   = (u16*)(ws + (66L  << 20));   // 1M
    u16* wqn  = (u16*)(ws + (68L  << 20));   // 4M
    u16* wo   = (u16*)(ws + (76L  << 20));   // 4M
    u16* wkbk = (u16*)(ws + (84L  << 20));   // 1M
    u16* wkbv = (u16*)(ws + (86L  << 20));   // 1M
    u16* wup  = (u16*)(ws + (88L  << 20));   // 16M
    u16* wdn  = (u16*)(ws + (120L << 20));   // 16M
    u16* bkk  = (u16*)(ws + (152L << 20));   // kb_keys bf16, 0.5M
    u16* bkv  = (u16*)(ws + (153L << 20));   // kb_values bf16, 0.5M

    const bool fast = ws_size >= (154L << 20);
    const dim3 blk(256);

    rmsnorm_k<<<2048, blk, 0, stream>>>(hidden, ln1_w, xn);

    if (fast) {
        cvt_bf16<<<2048, blk, 0, stream>>>(q_w,    wq,   4194304);
        cvt_bf16<<<512,  blk, 0, stream>>>(k_w,    wk,   1048576);
        cvt_bf16<<<512,  blk, 0, stream>>>(v_w,    wv,   1048576);
        cvt_bf16<<<2048, blk, 0, stream>>>(qnew_w, wqn,  4194304);
        cvt_bf16<<<2048, blk, 0, stream>>>(o_w,    wo,   4194304);
        cvt_bf16<<<512,  blk, 0, stream>>>(kbk_w,  wkbk, 1048576);
        cvt_bf16<<<512,  blk, 0, stream>>>(kbv_w,  wkbv, 1048576);
        cvt_bf16<<<8192, blk, 0, stream>>>(up_w,   wup,  16777216);
        cvt_bf16<<<8192, blk, 0, stream>>>(down_w, wdn,  16777216);
        cvt_bf16<<<256,  blk, 0, stream>>>(kb_keys, bkk, 524288);
        cvt_bf16<<<256,  blk, 0, stream>>>(kb_vals, bkv, 524288);

        gemm_fast<0, false, false><<<dim3(16, 16), blk, 0, stream>>>(xn, wq,  q,  nullptr, 2048, 2048, 2048, 2048, 0);
        gemm_fast<0, false, false><<<dim3(4, 16),  blk, 0, stream>>>(xn, wk,  k,  nullptr, 2048, 512,  2048, 512,  0);
        gemm_fast<0, true,  false><<<dim3(4, 16),  blk, 0, stream>>>(xn, wv,  vT, nullptr, 2048, 512,  2048, 2048, 0);
        gemm_fast<0, false, false><<<dim3(16, 16), blk, 0, stream>>>(xn, wqn, qn, nullptr, 2048, 2048, 2048, 2048, 0);
        gemm_fast<0, false, false><<<dim3(4, 2),   blk, 0, stream>>>(bkk, wkbk, kbk,  nullptr, 256, 512, 2048, 512, 1);
        gemm_fast<0, true,  false><<<dim3(4, 2),   blk, 0, stream>>>(bkv, wkbv, kbvT, nullptr, 256, 512, 2048, 320, 1);
    } else {
        gemm_bt<0, false, true,  false><<<dim3(16, 16), blk, 0, stream>>>(xn, q_w,    q,  nullptr, 2048, 2048, 2048, 2048, 0);
        gemm_bt<0, false, true,  false><<<dim3(4, 16),  blk, 0, stream>>>(xn, k_w,    k,  nullptr, 2048, 512,  2048, 512,  0);
        gemm_bt<0, true,  true,  false><<<dim3(4, 16),  blk, 0, stream>>>(xn, v_w,    vT, nullptr, 2048, 512,  2048, 2048, 0);
        gemm_bt<0, false, true,  false><<<dim3(16, 16), blk, 0, stream>>>(xn, qnew_w, qn, nullptr, 2048, 2048, 2048, 2048, 0);
        gemm_bt<0, false, false, false><<<dim3(4, 2),   blk, 0, stream>>>(kb_keys, kbk_w, kbk,  nullptr, 256, 512, 2048, 512, 1);
        gemm_bt<0, true,  false, false><<<dim3(4, 2),   blk, 0, stream>>>(kb_vals, kbv_w, kbvT, nullptr, 256, 512, 2048, 320, 1);
    }
    sink_copy<<<2, blk, 0, stream>>>(sink_k, sink_v, kbk, kbvT);
    kbk_clear<<<126, blk, 0, stream>>>(kbk);

    rope_k<<<2048, blk, 0, stream>>>(q, 2048, pos_ids);
    rope_k<<<2048, blk, 0, stream>>>(k, 512, pos_ids);

    attn_kernel<<<dim3(32, 32), blk, 0, stream>>>(q, qn, k, vT, kbk, kbvT, attn);

    if (fast) {
        gemm_fast<1, false, true ><<<dim3(16, 16), blk, 0, stream>>>(attn, wo, hbuf, hidden, 2048, 2048, 2048, 2048, 0);
        rmsnorm_k<<<2048, blk, 0, stream>>>(hbuf, ln2_w, xn);
        gemm_fast<2, false, false><<<dim3(64, 16), blk, 0, stream>>>(xn, wup, act, nullptr, 2048, 8192, 2048, 8192, 0);
        gemm_fast<1, false, true ><<<dim3(16, 16), blk, 0, stream>>>(act, wdn, out, hbuf, 2048, 2048, 8192, 2048, 0);
    } else {
        gemm_bt<1, false, true, true ><<<dim3(16, 16), blk, 0, stream>>>(attn, o_w, hbuf, hidden, 2048, 2048, 2048, 2048, 0);
        rmsnorm_k<<<2048, blk, 0, stream>>>(hbuf, ln2_w, xn);
        gemm_bt<2, false, true, false><<<dim3(64, 16), blk, 0, stream>>>(xn, up_w, act, nullptr, 2048, 8192, 2048, 8192, 0);
        gemm_bt<1, false, true, true ><<<dim3(16, 16), blk, 0, stream>>>(act, down_w, out, hbuf, 2048, 2048, 8192, 2048, 0);
    }
}

// Round 5
// 1100.357 us; speedup vs baseline: 1.4849x; 1.0957x over previous
//
#include <hip/hip_runtime.h>
#include <hip/hip_bf16.h>

typedef __attribute__((ext_vector_type(8))) short bf16x8;
typedef __attribute__((ext_vector_type(8))) unsigned short u16x8;
typedef __attribute__((ext_vector_type(4))) float f32x4;
typedef unsigned short u16;

__device__ __forceinline__ float bf2f(u16 u) {
    union { unsigned int i; float f; } v; v.i = ((unsigned int)u) << 16; return v.f;
}
__device__ __forceinline__ u16 f2bf(float f) {
    union { float f; unsigned int i; } v; v.f = f;
    unsigned int r = v.i + 0x7fffu + ((v.i >> 16) & 1u);
    return (u16)(r >> 16);
}
__device__ __forceinline__ u16x8 pack8(const float4& a, const float4& b) {
    u16x8 r;
    r[0] = f2bf(a.x); r[1] = f2bf(a.y); r[2] = f2bf(a.z); r[3] = f2bf(a.w);
    r[4] = f2bf(b.x); r[5] = f2bf(b.y); r[6] = f2bf(b.z); r[7] = f2bf(b.w);
    return r;
}

#define GLD16(gp, lp) __builtin_amdgcn_global_load_lds( \
    (const __attribute__((address_space(1))) void*)(gp), \
    (__attribute__((address_space(3))) void*)(lp), 16, 0, 0)

// ======== FAST GEMM (all-bf16, global_load_lds 16B staging, m97 structure) ====
template <int EPI, bool TRANS, bool OUTF>
__global__ __launch_bounds__(256) void gemm_fast(
    const u16* __restrict__ A, const u16* __restrict__ B,
    void* __restrict__ Cv, const float* __restrict__ ADD,
    int M, int N, int K, int ldc, int m_off)
{
    __shared__ u16 As[128 * 32];   // [128 rows][32 k] unpadded (GLD contract)
    __shared__ u16 Bs[128 * 32];
    const int tid = threadIdx.x;
    const int w = tid >> 6, lane = tid & 63;
    const int col = lane & 15, quad = lane >> 4;
    const long m0 = (long)blockIdx.y * 128, n0 = (long)blockIdx.x * 128;
    const int wr = (w >> 1) * 64, wc = (w & 1) * 64;
    const int srow = lane >> 2;          // 0..15
    const int scol = (lane & 3) * 8;     // element col within 32-wide k-tile

    const f32x4 fzero = {0.f, 0.f, 0.f, 0.f};
    f32x4 acc[4][4];
#pragma unroll
    for (int i = 0; i < 4; ++i)
#pragma unroll
        for (int t = 0; t < 4; ++t) acc[i][t] = fzero;

    const u16* Ab = A + m0 * (long)K + scol;
    const u16* Bb = B + n0 * (long)K + scol;
    for (int k0 = 0; k0 < K; k0 += 32) {
        __syncthreads();   // prior-iter ds_reads done before overwrite
#pragma unroll
        for (int c = 0; c < 2; ++c) {
            const int rr = w * 32 + c * 16;   // wave-uniform LDS base
            GLD16(Ab + (long)(rr + srow) * K + k0, &As[rr * 32]);
            GLD16(Bb + (long)(rr + srow) * K + k0, &Bs[rr * 32]);
        }
        __syncthreads();   // compiler drains vmcnt before barrier
        bf16x8 af[4], bfr[4];
#pragma unroll
        for (int i = 0; i < 4; ++i)
            af[i] = *(const bf16x8*)&As[(wr + i * 16 + col) * 32 + quad * 8];
#pragma unroll
        for (int t = 0; t < 4; ++t)
            bfr[t] = *(const bf16x8*)&Bs[(wc + t * 16 + col) * 32 + quad * 8];
#pragma unroll
        for (int i = 0; i < 4; ++i)
#pragma unroll
            for (int t = 0; t < 4; ++t)
                acc[i][t] = __builtin_amdgcn_mfma_f32_16x16x32_bf16(af[i], bfr[t], acc[i][t], 0, 0, 0);
    }

#pragma unroll
    for (int i = 0; i < 4; ++i)
#pragma unroll
        for (int t = 0; t < 4; ++t)
#pragma unroll
            for (int r = 0; r < 4; ++r) {
                const long m = m0 + wr + i * 16 + quad * 4 + r;  // C/D: row = quad*4+reg
                const long n = n0 + wc + t * 16 + col;           // C/D: col = lane&15
                float v = acc[i][t][r];
                if (EPI == 1) v += ADD[m * N + n];
                if (EPI == 2) { float rv = v > 0.f ? v : 0.f; v = rv * rv; }
                const long idx = TRANS ? (n * (long)ldc + m + m_off)
                                       : ((m + m_off) * (long)ldc + n);
                if (OUTF) ((float*)Cv)[idx] = v;
                else      ((u16*)Cv)[idx]   = f2bf(v);
            }
}

// ======== FALLBACK GEMM (fp32 B) ==============================================
template <int EPI, bool TRANS, bool ABF, bool OUTF>
__global__ __launch_bounds__(256) void gemm_bt(
    const void* __restrict__ Av, const float* __restrict__ B,
    void* __restrict__ Cv, const float* __restrict__ ADD,
    int M, int N, int K, int ldc, int m_off)
{
    __shared__ alignas(16) u16 As[128 * 32];
    __shared__ alignas(16) u16 Bs[128 * 32];
    const int tid = threadIdx.x;
    const int w = tid >> 6, lane = tid & 63;
    const int col = lane & 15, quad = lane >> 4;
    const long m0 = (long)blockIdx.y * 128, n0 = (long)blockIdx.x * 128;
    const int wr = (w >> 1) * 64, wc = (w & 1) * 64;
    const int srow = tid >> 1;
    const int scol = (tid & 1) * 16;

    const f32x4 fzero = {0.f, 0.f, 0.f, 0.f};
    f32x4 acc[4][4];
#pragma unroll
    for (int i = 0; i < 4; ++i)
#pragma unroll
        for (int t = 0; t < 4; ++t) acc[i][t] = fzero;

    const u16*   Ab  = ABF ? (const u16*)Av   + (m0 + srow) * (long)K + scol : nullptr;
    const float* Afp = ABF ? nullptr : (const float*)Av + (m0 + srow) * (long)K + scol;
    const float* Bf  = B + (n0 + srow) * (long)K + scol;
    u16* AsW = &As[srow * 32 + scol];
    u16* BsW = &Bs[srow * 32 + scol];

    for (int k0 = 0; k0 < K; k0 += 32) {
        u16x8 a0, a1, b0, b1;
        if (ABF) {
            a0 = *(const u16x8*)(Ab + k0);
            a1 = *(const u16x8*)(Ab + k0 + 8);
        } else {
            float4 f0 = *(const float4*)(Afp + k0);
            float4 f1 = *(const float4*)(Afp + k0 + 4);
            float4 f2_ = *(const float4*)(Afp + k0 + 8);
            float4 f3 = *(const float4*)(Afp + k0 + 12);
            a0 = pack8(f0, f1); a1 = pack8(f2_, f3);
        }
        {
            float4 g0 = *(const float4*)(Bf + k0);
            float4 g1 = *(const float4*)(Bf + k0 + 4);
            float4 g2 = *(const float4*)(Bf + k0 + 8);
            float4 g3 = *(const float4*)(Bf + k0 + 12);
            b0 = pack8(g0, g1); b1 = pack8(g2, g3);
        }
        __syncthreads();
        *(u16x8*)(AsW)     = a0;
        *(u16x8*)(AsW + 8) = a1;
        *(u16x8*)(BsW)     = b0;
        *(u16x8*)(BsW + 8) = b1;
        __syncthreads();
        bf16x8 af[4], bfr[4];
#pragma unroll
        for (int i = 0; i < 4; ++i)
            af[i] = *(const bf16x8*)&As[(wr + i * 16 + col) * 32 + quad * 8];
#pragma unroll
        for (int t = 0; t < 4; ++t)
            bfr[t] = *(const bf16x8*)&Bs[(wc + t * 16 + col) * 32 + quad * 8];
#pragma unroll
        for (int i = 0; i < 4; ++i)
#pragma unroll
            for (int t = 0; t < 4; ++t)
                acc[i][t] = __builtin_amdgcn_mfma_f32_16x16x32_bf16(af[i], bfr[t], acc[i][t], 0, 0, 0);
    }

#pragma unroll
    for (int i = 0; i < 4; ++i)
#pragma unroll
        for (int t = 0; t < 4; ++t)
#pragma unroll
            for (int r = 0; r < 4; ++r) {
                const long m = m0 + wr + i * 16 + quad * 4 + r;
                const long n = n0 + wc + t * 16 + col;
                float v = acc[i][t][r];
                if (EPI == 1) v += ADD[m * N + n];
                if (EPI == 2) { float rv = v > 0.f ? v : 0.f; v = rv * rv; }
                const long idx = TRANS ? (n * (long)ldc + m + m_off)
                                       : ((m + m_off) * (long)ldc + n);
                if (OUTF) ((float*)Cv)[idx] = v;
                else      ((u16*)Cv)[idx]   = f2bf(v);
            }
}

// ======== fp32 -> bf16 bulk convert ===========================================
__global__ __launch_bounds__(256) void cvt_bf16(
    const float* __restrict__ in, u16* __restrict__ out, int n)
{
    const long i = ((long)blockIdx.x * 256 + threadIdx.x) * 8;
    if (i + 8 <= n) {
        float4 f0 = *(const float4*)(in + i);
        float4 f1 = *(const float4*)(in + i + 4);
        *(u16x8*)(out + i) = pack8(f0, f1);
    }
}

// ======== RMSNorm: fp32 in (X, W), bf16 out ===================================
__global__ __launch_bounds__(256) void rmsnorm_k(
    const float* __restrict__ X, const float* __restrict__ W, u16* __restrict__ out)
{
    const int row = blockIdx.x, tid = threadIdx.x;
    const float* xr = X + (long)row * 2048 + tid * 8;
    float4 x0 = *(const float4*)xr;
    float4 x1 = *(const float4*)(xr + 4);
    float xs[8] = {x0.x, x0.y, x0.z, x0.w, x1.x, x1.y, x1.z, x1.w};
    float local = 0.f;
#pragma unroll
    for (int j = 0; j < 8; ++j) local += xs[j] * xs[j];
#pragma unroll
    for (int off = 32; off >= 1; off >>= 1) local += __shfl_xor(local, off, 64);
    __shared__ float ssum[4];
    if ((tid & 63) == 0) ssum[tid >> 6] = local;
    __syncthreads();
    const float tot = ssum[0] + ssum[1] + ssum[2] + ssum[3];
    const float rs = rsqrtf(tot * (1.f / 2048.f) + 1e-5f);
    float4 w0 = *(const float4*)(W + tid * 8);
    float4 w1 = *(const float4*)(W + tid * 8 + 4);
    float wsv[8] = {w0.x, w0.y, w0.z, w0.w, w1.x, w1.y, w1.z, w1.w};
    u16x8 ov;
#pragma unroll
    for (int j = 0; j < 8; ++j) ov[j] = f2bf(xs[j] * rs * wsv[j]);
    *(u16x8*)(out + (long)row * 2048 + tid * 8) = ov;
}

// ======== RoPE in-place on bf16 [2048][ncols] =================================
__global__ __launch_bounds__(256) void rope_k(
    u16* __restrict__ T, int ncols, const int* __restrict__ pos)
{
    const int s = blockIdx.x;
    const float p = (float)pos[s];
    u16* row = T + (long)s * ncols;
    for (int idx = threadIdx.x; idx < (ncols >> 1); idx += 256) {
        const int chunk = idx >> 5, d = idx & 31;
        const float inv = expf(-0.28782313662425572f * (float)d); // 10000^(-d/32)
        const float ang = p * inv;
        const float c = cosf(ang), sn = sinf(ang);
        const int i0 = chunk * 64 + d;
        const float x0 = bf2f(row[i0]), x1 = bf2f(row[i0 + 32]);
        row[i0]      = f2bf(x0 * c - x1 * sn);
        row[i0 + 32] = f2bf(x1 * c + x0 * sn);
    }
}

// ======== sink token + kbk tail clear =========================================
__global__ void sink_copy(const float* __restrict__ sk, const float* __restrict__ sv,
                          u16* __restrict__ kbk, u16* __restrict__ kbvT)
{
    const int i = blockIdx.x * 256 + threadIdx.x;
    if (i < 512) { kbk[i] = f2bf(sk[i]); kbvT[(long)i * 320] = f2bf(sv[i]); }
}
__global__ void kbk_clear(u16* __restrict__ kbk)
{
    const int i = blockIdx.x * 256 + threadIdx.x;
    if (i < 63 * 512) kbk[257 * 512 + i] = 0;
}

// ======== Rectangular attention (KB || causal self, joint softmax) ============
// No-max softmax (scores bounded; shift-invariant), wave-synchronous LDS P
// round-trip (no barriers — each wave owns Plds[w]), deferred l-reduction,
// qt remapped for per-CU load balance.
__global__ __launch_bounds__(256) void attn_kernel(
    const u16* __restrict__ Q, const u16* __restrict__ QN,
    const u16* __restrict__ Ks, const u16* __restrict__ VT,
    const u16* __restrict__ KBK, const u16* __restrict__ KBVT,
    u16* __restrict__ O)
{
    const int h = blockIdx.y;
    const int qt = (blockIdx.x + blockIdx.y) & 31;   // load-balance remap
    const int s0 = qt * 64, kv = h >> 2;
    const int tid = threadIdx.x, w = tid >> 6, lane = tid & 63;
    const int col = lane & 15, quad = lane >> 4;
    const int rowbase = s0 + w * 16;
    __shared__ alignas(16) u16 Plds[4][16][64];
    const f32x4 fzero = {0.f, 0.f, 0.f, 0.f};

    bf16x8 af[2][2];
    {
        const u16* qp = QN + (long)(rowbase + col) * 2048 + h * 64 + quad * 8;
        af[0][0] = *(const bf16x8*)qp;
        af[0][1] = *(const bf16x8*)(qp + 32);
        const u16* qp2 = Q + (long)(rowbase + col) * 2048 + h * 64 + quad * 8;
        af[1][0] = *(const bf16x8*)qp2;
        af[1][1] = *(const bf16x8*)(qp2 + 32);
    }
    float l_run[4] = {0.f, 0.f, 0.f, 0.f};   // per-thread partial; reduced at end
    f32x4 o_acc[4];
#pragma unroll
    for (int t = 0; t < 4; ++t) o_acc[t] = fzero;

    for (int phase = 0; phase < 2; ++phase) {
        const u16* Kp = phase ? Ks : KBK;
        const u16* Vp = phase ? VT : KBVT;
        const long ldv = phase ? 2048 : 320;
        const int iters = phase ? (qt + 1) : 5;
        const bf16x8 a0 = af[phase][0], a1 = af[phase][1];
        for (int it = 0; it < iters; ++it) {
            const int key0 = it * 64;
            f32x4 sv[4];
#pragma unroll
            for (int t = 0; t < 4; ++t) {
                const u16* kp = Kp + (long)(key0 + t * 16 + col) * 512 + kv * 64 + quad * 8;
                bf16x8 k0v = *(const bf16x8*)kp;
                bf16x8 k1v = *(const bf16x8*)(kp + 32);
                f32x4 z = fzero;
                z = __builtin_amdgcn_mfma_f32_16x16x32_bf16(a0, k0v, z, 0, 0, 0);
                sv[t] = __builtin_amdgcn_mfma_f32_16x16x32_bf16(a1, k1v, z, 0, 0, 0);
            }
            // p = exp(s/8), masked -> 0 (shift-invariant softmax; no running max)
#pragma unroll
            for (int t = 0; t < 4; ++t)
#pragma unroll
                for (int r = 0; r < 4; ++r) {
                    const int key = key0 + t * 16 + col;
                    const bool msk = phase ? (key > rowbase + quad * 4 + r) : (key >= 257);
                    const float p = msk ? 0.f : __expf(sv[t][r] * 0.125f);
                    l_run[r] += p;
                    Plds[w][quad * 4 + r][t * 16 + col] = f2bf(p);  // C-layout dump
                }
            // wave-synchronous: same-wave DS ops complete in order — no barrier
            const bf16x8 p0 = *(const bf16x8*)&Plds[w][col][quad * 8];       // A-layout
            const bf16x8 p1 = *(const bf16x8*)&Plds[w][col][32 + quad * 8];
#pragma unroll
            for (int t = 0; t < 4; ++t) {
                const u16* vp = Vp + (long)(kv * 64 + t * 16 + col) * ldv + key0 + quad * 8;
                bf16x8 v0 = *(const bf16x8*)vp;
                bf16x8 v1 = *(const bf16x8*)(vp + 32);
                o_acc[t] = __builtin_amdgcn_mfma_f32_16x16x32_bf16(p0, v0, o_acc[t], 0, 0, 0);
                o_acc[t] = __builtin_amdgcn_mfma_f32_16x16x32_bf16(p1, v1, o_acc[t], 0, 0, 0);
            }
        }
    }
    // one l-reduction across the 16 lanes sharing each q-row
#pragma unroll
    for (int off = 1; off < 16; off <<= 1)
#pragma unroll
        for (int r = 0; r < 4; ++r)
            l_run[r] += __shfl_xor(l_run[r], off, 64);
#pragma unroll
    for (int t = 0; t < 4; ++t)
#pragma unroll
        for (int r = 0; r < 4; ++r) {
            const long m = rowbase + quad * 4 + r;
            const long n = h * 64 + t * 16 + col;
            O[m * 2048 + n] = f2bf(o_acc[t][r] / l_run[r]);
        }
}

// ======== launcher ============================================================
extern "C" void kernel_launch(void* const* d_in, const int* in_sizes, int n_in,
                              void* d_out, int out_size, void* d_ws, size_t ws_size,
                              hipStream_t stream)
{
    const float* hidden  = (const float*)d_in[0];
    const float* kb_keys = (const float*)d_in[1];
    const float* kb_vals = (const float*)d_in[2];
    const float* q_w     = (const float*)d_in[3];
    const float* k_w     = (const float*)d_in[4];
    const float* v_w     = (const float*)d_in[5];
    const float* o_w     = (const float*)d_in[6];
    const float* qnew_w  = (const float*)d_in[7];
    const float* kbk_w   = (const float*)d_in[8];
    const float* kbv_w   = (const float*)d_in[9];
    const float* sink_k  = (const float*)d_in[10];
    const float* sink_v  = (const float*)d_in[11];
    const float* ln1_w   = (const float*)d_in[12];
    const float* ln2_w   = (const float*)d_in[13];
    const float* up_w    = (const float*)d_in[14];
    const float* down_w  = (const float*)d_in[15];
    const int*   pos_ids = (const int*)d_in[16];
    float* out = (float*)d_out;

    // Activations: 56 MB (act overlaps dead q/qn/k/vT/kb/attn).
    char* ws = (char*)d_ws;
    u16*   xn   = (u16*)(ws);                                // bf16 [2048][2048]  0..8MB
    float* hbuf = (float*)(ws + (8L  << 20));                // fp32 [2048][2048]  8..24MB
    u16*   q    = (u16*)(ws + (24L << 20));                  // bf16 24..32MB
    u16*   qn   = (u16*)(ws + (32L << 20));                  // bf16 32..40MB
    u16*   k    = (u16*)(ws + (40L << 20));                  // bf16 40..42MB
    u16*   vT   = (u16*)(ws + (42L << 20));                  // bf16 42..44MB
    u16*   kbk  = (u16*)(ws + (44L << 20));                  // bf16 [320][512]
    u16*   kbvT = (u16*)(ws + (44L << 20) + 320 * 512 * 2);  // bf16 [512][320]
    u16*   attn = (u16*)(ws + (45L << 20));                  // bf16 45..53MB
    u16*   act  = (u16*)(ws + (24L << 20));                  // bf16 24..56MB (after attn)

    // bf16 weight cache: 56..154 MB
    u16* wq   = (u16*)(ws + (56L  << 20));
    u16* wk   = (u16*)(ws + (64L  << 20));
    u16* wv   = (u16*)(ws + (66L  << 20));
    u16* wqn  = (u16*)(ws + (68L  << 20));
    u16* wo   = (u16*)(ws + (76L  << 20));
    u16* wkbk = (u16*)(ws + (84L  << 20));
    u16* wkbv = (u16*)(ws + (86L  << 20));
    u16* wup  = (u16*)(ws + (88L  << 20));
    u16* wdn  = (u16*)(ws + (120L << 20));
    u16* bkk  = (u16*)(ws + (152L << 20));
    u16* bkv  = (u16*)(ws + (153L << 20));

    const bool fast = ws_size >= (154L << 20);
    const dim3 blk(256);

    rmsnorm_k<<<2048, blk, 0, stream>>>(hidden, ln1_w, xn);

    if (fast) {
        cvt_bf16<<<2048, blk, 0, stream>>>(q_w,    wq,   4194304);
        cvt_bf16<<<512,  blk, 0, stream>>>(k_w,    wk,   1048576);
        cvt_bf16<<<512,  blk, 0, stream>>>(v_w,    wv,   1048576);
        cvt_bf16<<<2048, blk, 0, stream>>>(qnew_w, wqn,  4194304);
        cvt_bf16<<<2048, blk, 0, stream>>>(o_w,    wo,   4194304);
        cvt_bf16<<<512,  blk, 0, stream>>>(kbk_w,  wkbk, 1048576);
        cvt_bf16<<<512,  blk, 0, stream>>>(kbv_w,  wkbv, 1048576);
        cvt_bf16<<<8192, blk, 0, stream>>>(up_w,   wup,  16777216);
        cvt_bf16<<<8192, blk, 0, stream>>>(down_w, wdn,  16777216);
        cvt_bf16<<<256,  blk, 0, stream>>>(kb_keys, bkk, 524288);
        cvt_bf16<<<256,  blk, 0, stream>>>(kb_vals, bkv, 524288);

        gemm_fast<0, false, false><<<dim3(16, 16), blk, 0, stream>>>(xn, wq,  q,  nullptr, 2048, 2048, 2048, 2048, 0);
        gemm_fast<0, false, false><<<dim3(4, 16),  blk, 0, stream>>>(xn, wk,  k,  nullptr, 2048, 512,  2048, 512,  0);
        gemm_fast<0, true,  false><<<dim3(4, 16),  blk, 0, stream>>>(xn, wv,  vT, nullptr, 2048, 512,  2048, 2048, 0);
        gemm_fast<0, false, false><<<dim3(16, 16), blk, 0, stream>>>(xn, wqn, qn, nullptr, 2048, 2048, 2048, 2048, 0);
        gemm_fast<0, false, false><<<dim3(4, 2),   blk, 0, stream>>>(bkk, wkbk, kbk,  nullptr, 256, 512, 2048, 512, 1);
        gemm_fast<0, true,  false><<<dim3(4, 2),   blk, 0, stream>>>(bkv, wkbv, kbvT, nullptr, 256, 512, 2048, 320, 1);
    } else {
        gemm_bt<0, false, true,  false><<<dim3(16, 16), blk, 0, stream>>>(xn, q_w,    q,  nullptr, 2048, 2048, 2048, 2048, 0);
        gemm_bt<0, false, true,  false><<<dim3(4, 16),  blk, 0, stream>>>(xn, k_w,    k,  nullptr, 2048, 512,  2048, 512,  0);
        gemm_bt<0, true,  true,  false><<<dim3(4, 16),  blk, 0, stream>>>(xn, v_w,    vT, nullptr, 2048, 512,  2048, 2048, 0);
        gemm_bt<0, false, true,  false><<<dim3(16, 16), blk, 0, stream>>>(xn, qnew_w, qn, nullptr, 2048, 2048, 2048, 2048, 0);
        gemm_bt<0, false, false, false><<<dim3(4, 2),   blk, 0, stream>>>(kb_keys, kbk_w, kbk,  nullptr, 256, 512, 2048, 512, 1);
        gemm_bt<0, true,  false, false><<<dim3(4, 2),   blk, 0, stream>>>(kb_vals, kbv_w, kbvT, nullptr, 256, 512, 2048, 320, 1);
    }
    sink_copy<<<2, blk, 0, stream>>>(sink_k, sink_v, kbk, kbvT);
    kbk_clear<<<126, blk, 0, stream>>>(kbk);

    rope_k<<<2048, blk, 0, stream>>>(q, 2048, pos_ids);
    rope_k<<<2048, blk, 0, stream>>>(k, 512, pos_ids);

    attn_kernel<<<dim3(32, 32), blk, 0, stream>>>(q, qn, k, vT, kbk, kbvT, attn);

    if (fast) {
        gemm_fast<1, false, true ><<<dim3(16, 16), blk, 0, stream>>>(attn, wo, hbuf, hidden, 2048, 2048, 2048, 2048, 0);
        rmsnorm_k<<<2048, blk, 0, stream>>>(hbuf, ln2_w, xn);
        gemm_fast<2, false, false><<<dim3(64, 16), blk, 0, stream>>>(xn, wup, act, nullptr, 2048, 8192, 2048, 8192, 0);
        gemm_fast<1, false, true ><<<dim3(16, 16), blk, 0, stream>>>(act, wdn, out, hbuf, 2048, 2048, 8192, 2048, 0);
    } else {
        gemm_bt<1, false, true, true ><<<dim3(16, 16), blk, 0, stream>>>(attn, o_w, hbuf, hidden, 2048, 2048, 2048, 2048, 0);
        rmsnorm_k<<<2048, blk, 0, stream>>>(hbuf, ln2_w, xn);
        gemm_bt<2, false, true, false><<<dim3(64, 16), blk, 0, stream>>>(xn, up_w, act, nullptr, 2048, 8192, 2048, 8192, 0);
        gemm_bt<1, false, true, true ><<<dim3(16, 16), blk, 0, stream>>>(act, down_w, out, hbuf, 2048, 2048, 8192, 2048, 0);
    }
}